// Round 1
// baseline (94.953 us; speedup 1.0000x reference)
//
#include <hip/hip_runtime.h>
#include <hip/hip_bf16.h>

// CapsuleLayer dynamic routing, MI355X. fp32 in/out.
// C=10, B=128, N=1152, IN=8, OUT=16, 3 routing iters.
//
// v9 (round 11): two changes on top of v8 (P in LDS, bf16x2, G=2).
//  1. XCD-chunked block swizzle. Default round-robin dispatch puts ~8
//     distinct c's resident per XCD -> W working set 8x590KB = 4.7 MB > 4 MB
//     L2 -> every W re-read falls to L3. Aggregate ~420 MB L3 reads / 45 us
//     = ~9 TB/s ~= L3 ceiling; block time (36 us) matches 664 KB / per-block
//     L3 share exactly. Chunked remap (blk = (bid%8)*80 + bid/8) gives each
//     XCD a contiguous 80-block chunk -> <=2 c's -> W ws <=1.18 MB, L2-fits.
//  2. Parallel squash. The old t<32 combine serialized 1 of 16 waves between
//     two barriers, 3x per kernel. Now every thread redundantly combines its
//     own o-quad from lds_s (broadcast ds_read_b128, free) + quad butterfly
//     for ||s||^2; barrier B and lds_out are gone. WAR on lds_s handled by
//     per-iteration parity double-buffer (+1 KB LDS, still 2 blocks/CU).
//
// Structure: G=2, 512 thr, one block per (c, b-pair), 640 blocks.
//   Lane l: o-quad q=l&3 (owns o=q*4..+3), row-sub r=l>>2; wave w covers rows
//   [w*144,(w+1)*144) in 9 passes of 16. W float4 load = 16 rows x 64 B fully-
//   consumed lines. fp32 accumulation everywhere; only P storage is bf16
//   (absmax 0.0078 vs threshold 0.0172, 2.2x margin). Logit state eliminated:
//   logit = dot(accum-out, P) recomputed per iter. Unnormalized softmax
//   (|logit| <~ 30, fp32-safe). ldsP slots are thread-private: no barrier in
//   the P pipeline (lgkmcnt orders same-thread RAW); ds b64 at 8B lane stride
//   = 2-way bank aliasing = free (m136).

constexpr int C = 10, B = 128, N = 1152, IN = 8, OUT = 16;
constexpr int THREADS = 512;
constexpr int NW = THREADS / 64;          // 8 waves
constexpr int G = 2;                      // batches per block
constexpr int PASSES = N / (NW * 16);     // 9
constexpr int NBLK = C * (B / G);         // 640
constexpr int NXCD = 8;
constexpr int CHUNK = NBLK / NXCD;        // 80 (640 % 8 == 0: bijective)

__device__ __forceinline__ unsigned packbf(float a, float b) {
    __hip_bfloat162 h = __float22bfloat162_rn(float2{a, b});  // RNE
    return *(unsigned*)&h;
}
__device__ __forceinline__ float bflo(unsigned u) { return __uint_as_float(u << 16); }
__device__ __forceinline__ float bfhi(unsigned u) { return __uint_as_float(u & 0xffff0000u); }

__global__ __launch_bounds__(THREADS)
void caps_route(const float* __restrict__ Xf, const float* __restrict__ Wf,
                float* __restrict__ Of) {
    // P packed: .x = bf16x2(P0,P1), .y = bf16x2(P2,P3); thread-private slots
    __shared__ uint2 ldsP[G * PASSES * THREADS];       // 73,728 B
    __shared__ float lds_s[2][G][NW][OUT];             // parity-buffered wave sums
    __shared__ float lds_sum[2][G][NW];                // parity-buffered denoms

    const int t = threadIdx.x;
    const int l = t & 63;
    const int wid = t >> 6;
    const int q = l & 3;        // o-quad: owns o = q*4 .. q*4+3
    const int rsub = l >> 2;    // row-sub within a pass (0..15)

    // XCD-chunked swizzle: physical bid%8 -> XCD (round-robin dispatch).
    // Give XCD x the contiguous logical range [x*80, x*80+80).
    const int bid = blockIdx.x;
    const int blk = (bid & (NXCD - 1)) * CHUNK + (bid >> 3);
    const int c = blk >> 6;     // 64 consecutive logical blocks share c
    const int b0 = (blk & 63) * G;

    // ---- priors: P[n][o] = sum_i x[b,n,i] * W[c,n,i,o] (fp32 acc, bf16 store)
    #pragma unroll
    for (int p = 0; p < PASSES; ++p) {
        const int n = wid * (16 * PASSES) + p * 16 + rsub;
        const float4* wr = (const float4*)(Wf + (size_t)(c * N + n) * (IN * OUT));
        float4 wv[IN];
        #pragma unroll
        for (int i = 0; i < IN; ++i) wv[i] = wr[i * 4 + q];   // 16 full lines/instr
        #pragma unroll
        for (int g = 0; g < G; ++g) {
            const float4* xr = (const float4*)(Xf + (size_t)((b0 + g) * N + n) * IN);
            const float4 xa = xr[0], xc = xr[1];
            const float xs[8] = { xa.x, xa.y, xa.z, xa.w, xc.x, xc.y, xc.z, xc.w };
            float a0 = 0.f, a1 = 0.f, a2 = 0.f, a3 = 0.f;
            #pragma unroll
            for (int i = 0; i < IN; ++i) {
                a0 = fmaf(xs[i], wv[i].x, a0);
                a1 = fmaf(xs[i], wv[i].y, a1);
                a2 = fmaf(xs[i], wv[i].z, a2);
                a3 = fmaf(xs[i], wv[i].w, a3);
            }
            ldsP[(g * PASSES + p) * THREADS + t] =
                uint2{packbf(a0, a1), packbf(a2, a3)};
        }
    }

    // accumulated output quad-slice (fp32); logit[p] == dot(oa_full16, P[p])
    float oa[G][4];
    #pragma unroll
    for (int g = 0; g < G; ++g)
        #pragma unroll
        for (int k = 0; k < 4; ++k) oa[g][k] = 0.f;

    // ---- dynamic routing ----
    for (int it = 0; it < 3; ++it) {
        const int pb = it & 1;
        float s4[G][4];
        float ssum[G];
        if (it == 0) {
            // logits all 0 -> e = 1: plain sums
            #pragma unroll
            for (int g = 0; g < G; ++g) {
                ssum[g] = (float)PASSES;
                float a0 = 0.f, a1 = 0.f, a2 = 0.f, a3 = 0.f;
                #pragma unroll
                for (int p = 0; p < PASSES; ++p) {
                    const uint2 u = ldsP[(g * PASSES + p) * THREADS + t];
                    a0 += bflo(u.x); a1 += bfhi(u.x);
                    a2 += bflo(u.y); a3 += bfhi(u.y);
                }
                s4[g][0] = a0; s4[g][1] = a1; s4[g][2] = a2; s4[g][3] = a3;
            }
        } else {
            #pragma unroll
            for (int g = 0; g < G; ++g) {
                ssum[g] = 0.f;
                #pragma unroll
                for (int k = 0; k < 4; ++k) s4[g][k] = 0.f;
                #pragma unroll
                for (int p = 0; p < PASSES; ++p) {
                    const uint2 u = ldsP[(g * PASSES + p) * THREADS + t];
                    const float p0 = bflo(u.x), p1 = bfhi(u.x);
                    const float p2 = bflo(u.y), p3 = bfhi(u.y);
                    // logit[p] = dot(out_accum, P[p]) via quad butterfly
                    float d = oa[g][0] * p0;
                    d = fmaf(oa[g][1], p1, d);
                    d = fmaf(oa[g][2], p2, d);
                    d = fmaf(oa[g][3], p3, d);
                    d += __shfl_xor(d, 1, 64);
                    d += __shfl_xor(d, 2, 64);
                    const float e = __expf(d);      // replicated across quad
                    ssum[g] += e;
                    s4[g][0] = fmaf(e, p0, s4[g][0]);
                    s4[g][1] = fmaf(e, p1, s4[g][1]);
                    s4[g][2] = fmaf(e, p2, s4[g][2]);
                    s4[g][3] = fmaf(e, p3, s4[g][3]);
                }
            }
        }
        // reduce across the 16 row-subs of the wave (masks 4..32; quad bits
        // 0,1 carry replicas (ssum) / distinct o (s4) -> not summed)
        #pragma unroll
        for (int m = 4; m < 64; m <<= 1) {
            #pragma unroll
            for (int g = 0; g < G; ++g) {
                ssum[g] += __shfl_xor(ssum[g], m, 64);
                #pragma unroll
                for (int k = 0; k < 4; ++k) s4[g][k] += __shfl_xor(s4[g][k], m, 64);
            }
        }
        if (l < 4) {  // lane l == quad q: owns o = l*4..l*4+3
            #pragma unroll
            for (int g = 0; g < G; ++g)
                #pragma unroll
                for (int k = 0; k < 4; ++k) lds_s[pb][g][wid][l * 4 + k] = s4[g][k];
        }
        if (l == 0) {
            #pragma unroll
            for (int g = 0; g < G; ++g) lds_sum[pb][g][wid] = ssum[g];
        }
        __syncthreads();

        // all-thread redundant combine + squash (each thread: its own o-quad).
        // lds_s reads are 4 distinct addrs/wave (by q) -> 16-lane broadcast,
        // conflict-free. ||s||^2 completed across the quad via shfl_xor 1,2.
        float ov[G][4];
        #pragma unroll
        for (int g = 0; g < G; ++g) {
            float a0 = 0.f, a1 = 0.f, a2 = 0.f, a3 = 0.f, S = 0.f;
            #pragma unroll
            for (int w = 0; w < NW; ++w) {
                const float4 v = *(const float4*)&lds_s[pb][g][w][q * 4];
                a0 += v.x; a1 += v.y; a2 += v.z; a3 += v.w;
                S += lds_sum[pb][g][w];
            }
            const float inv = 1.f / S;
            const float s0 = a0 * inv, s1 = a1 * inv;
            const float s2 = a2 * inv, s3 = a3 * inv;
            float r = s0 * s0 + s1 * s1 + s2 * s2 + s3 * s3;
            r += __shfl_xor(r, 1, 64);
            r += __shfl_xor(r, 2, 64);
            const float sc = r / ((1.f + r) * sqrtf(r + 1e-8f));
            ov[g][0] = s0 * sc; ov[g][1] = s1 * sc;
            ov[g][2] = s2 * sc; ov[g][3] = s3 * sc;
        }
        if (it < 2) {
            #pragma unroll
            for (int g = 0; g < G; ++g)
                #pragma unroll
                for (int k = 0; k < 4; ++k) oa[g][k] += ov[g][k];
        } else if (t < 4) {  // wid==0, rsub==0, q==t: write final outputs
            #pragma unroll
            for (int g = 0; g < G; ++g)
                #pragma unroll
                for (int k = 0; k < 4; ++k)
                    Of[((size_t)c * B + b0 + g) * OUT + q * 4 + k] = ov[g][k];
        }
    }
}

extern "C" void kernel_launch(void* const* d_in, const int* in_sizes, int n_in,
                              void* d_out, int out_size, void* d_ws, size_t ws_size,
                              hipStream_t stream) {
    const float* X = (const float*)d_in[0];   // [B,N,IN] fp32
    const float* W = (const float*)d_in[1];   // [C,N,IN,OUT] fp32
    float* O = (float*)d_out;                 // [C,B,OUT] fp32
    hipLaunchKernelGGL(caps_route, dim3(NBLK), dim3(THREADS), 0, stream, X, W, O);
}